// Round 2
// baseline (369.006 us; speedup 1.0000x reference)
//
#include <hip/hip_runtime.h>
#include <hip/hip_bf16.h>

// GCN 2-layer: h = relu(Anorm @ (x@W1) + b1); out = Anorm @ (h@W2) + b2
// R11 changes vs R10 (latency-bound gather: raise bytes-in-flight):
//  - agg128_mm64: 256-thread blocks (16 nodes), gather unrolled to 16
//    edges in flight (q[16] uint4), __launch_bounds__(256,5).
//    LDS 20KB -> 5 resident blocks/CU, ~20 waves, ~320KB/CU in flight.
//  - aggregate64q: same U=16 deep unroll + __launch_bounds__(256,5).
//  - hq/h2q rows remain pre-scaled by dinv[row] (R10 invariant).

#define NTHREADS 256
#define BSH 9                 // bucket = dst >> 9 (512 nodes/bucket)
#define NBMAX 256

typedef unsigned int uint;
typedef unsigned short ushort;
typedef __attribute__((ext_vector_type(8))) short short8;
typedef __attribute__((ext_vector_type(4))) float floatx4;

__device__ __forceinline__ uint pack_bf16(float a, float b) {
    __hip_bfloat162 h = __float22bfloat162_rn(make_float2(a, b));
    return *reinterpret_cast<uint*>(&h);
}
__device__ __forceinline__ float bf16_lo(uint q) { return __uint_as_float(q << 16); }
__device__ __forceinline__ float bf16_hi(uint q) { return __uint_as_float(q & 0xffff0000u); }

// ---------- coarse bucket histogram only (no per-node atomics) ----------
__global__ __launch_bounds__(256) void bucket_hist_kernel(
    const int* __restrict__ dst, int* __restrict__ bcnt, int e, int nb) {
    __shared__ int hist[NBMAX];
    int t = threadIdx.x;
    for (int b = t; b < nb; b += 256) hist[b] = 0;
    __syncthreads();
    int e0 = blockIdx.x * 2048;
#pragma unroll
    for (int v = 0; v < 2; v++) {
        int gi = e0 + t * 8 + v * 4;
        if (gi + 3 < e) {
            int4 d4 = *(const int4*)&dst[gi];
            atomicAdd(&hist[d4.x >> BSH], 1);
            atomicAdd(&hist[d4.y >> BSH], 1);
            atomicAdd(&hist[d4.z >> BSH], 1);
            atomicAdd(&hist[d4.w >> BSH], 1);
        } else {
            for (int j = 0; j < 4; j++)
                if (gi + j < e) atomicAdd(&hist[dst[gi + j] >> BSH], 1);
        }
    }
    __syncthreads();
    for (int b = t; b < nb; b += 256) {
        int v = hist[b];
        if (v) atomicAdd(&bcnt[b], v);
    }
}

// ---------- bucket scan (nb <= 256, single block) ----------
__global__ void bucket_scan(const int* __restrict__ bcnt, int* __restrict__ bstart,
                            int* __restrict__ bcursor, int nb) {
    __shared__ int buf[NBMAX];
    int t = threadIdx.x;
    int v = (t < nb) ? bcnt[t] : 0;
    buf[t] = v;
    __syncthreads();
    int x = v;
    for (int off = 1; off < NBMAX; off <<= 1) {
        int y = (t >= off) ? buf[t - off] : 0;
        __syncthreads();
        x += y;
        buf[t] = x;
        __syncthreads();
    }
    if (t < nb) {
        bstart[t] = x - v;
        bcursor[t] = x - v;
    }
}

// ---------- coarse partition: staged[] = (src,dst) grouped by bucket ----------
__global__ __launch_bounds__(256) void partition_kernel(
    const int* __restrict__ src, const int* __restrict__ dst,
    int* __restrict__ bcursor, int2* __restrict__ staged, int e, int nb) {
    __shared__ int eS[2048];
    __shared__ int eD[2048];
    __shared__ int hist[NBMAX];
    __shared__ int base[NBMAX];
    int t = threadIdx.x;
    int e0 = blockIdx.x * 2048;

    for (int b = t; b < nb; b += 256) hist[b] = 0;
    __syncthreads();
#pragma unroll
    for (int v = 0; v < 2; v++) {
        int li = t * 8 + v * 4;
        int gi = e0 + li;
        int4 s4, d4;
        if (gi + 3 < e) {
            s4 = *(const int4*)&src[gi];
            d4 = *(const int4*)&dst[gi];
        } else {
            const int* sp = &src[gi];
            const int* dp = &dst[gi];
            s4.x = (gi + 0 < e) ? sp[0] : 0;  d4.x = (gi + 0 < e) ? dp[0] : -1;
            s4.y = (gi + 1 < e) ? sp[1] : 0;  d4.y = (gi + 1 < e) ? dp[1] : -1;
            s4.z = (gi + 2 < e) ? sp[2] : 0;  d4.z = (gi + 2 < e) ? dp[2] : -1;
            s4.w = (gi + 3 < e) ? sp[3] : 0;  d4.w = (gi + 3 < e) ? dp[3] : -1;
        }
        *(int4*)&eS[li] = s4;
        *(int4*)&eD[li] = d4;
        if (d4.x >= 0) atomicAdd(&hist[d4.x >> BSH], 1);
        if (d4.y >= 0) atomicAdd(&hist[d4.y >> BSH], 1);
        if (d4.z >= 0) atomicAdd(&hist[d4.z >> BSH], 1);
        if (d4.w >= 0) atomicAdd(&hist[d4.w >> BSH], 1);
    }
    __syncthreads();
    for (int b = t; b < nb; b += 256) {
        int v = hist[b];
        base[b] = v ? atomicAdd(&bcursor[b], v) : 0;
        hist[b] = 0;   // reset for rank pass
    }
    __syncthreads();
#pragma unroll
    for (int i = 0; i < 8; i++) {
        int li = t + i * 256;
        int d = eD[li];
        if (d >= 0) {
            int b = d >> BSH;
            int r = atomicAdd(&hist[b], 1);
            staged[base[b] + r] = make_int2(eS[li], d);
        }
    }
}

// ---------- per-bucket fused CSR: count+scan -> meta/dinv, then fill rec ----------
__global__ __launch_bounds__(256) void fine_csr_kernel(
    const int2* __restrict__ staged, const int* __restrict__ bstart,
    const int* __restrict__ bcnt, int4* __restrict__ meta,
    float* __restrict__ dinv, int* __restrict__ rec, int n) {
    __shared__ int lcnt[512];
    __shared__ int tsum[256];
    int b = blockIdx.x;
    int t = threadIdx.x;
    lcnt[t] = 0;
    lcnt[t + 256] = 0;
    __syncthreads();
    int s0 = bstart[b];
    int m = bcnt[b];
    for (int i = t; i < m; i += 256)
        atomicAdd(&lcnt[staged[s0 + i].y & 511], 1);
    __syncthreads();
    int v0 = lcnt[2 * t];
    int v1 = lcnt[2 * t + 1];
    int tot = v0 + v1;
    tsum[t] = tot;
    __syncthreads();
    int x = tot;
    for (int off = 1; off < 256; off <<= 1) {
        int y = (t >= off) ? tsum[t - off] : 0;
        __syncthreads();
        x += y;
        tsum[t] = x;
        __syncthreads();
    }
    int excl = x - tot;
    int node = (b << BSH) + 2 * t;
    if (node < n) {
        float di = rsqrtf((float)v0 + 1.0f);
        dinv[node] = di;
        meta[node] = make_int4(s0 + excl, v0, __float_as_int(di), __float_as_int(di * di));
    }
    if (node + 1 < n) {
        float di = rsqrtf((float)v1 + 1.0f);
        dinv[node + 1] = di;
        meta[node + 1] = make_int4(s0 + excl + v0, v1, __float_as_int(di), __float_as_int(di * di));
    }
    // repurpose lcnt as absolute cursors
    lcnt[2 * t] = s0 + excl;
    lcnt[2 * t + 1] = s0 + excl + v0;
    __syncthreads();
    // fill: rec[pos] = src (bucket segment is L2-hot from count pass)
    for (int i = t; i < m; i += 256) {
        int2 ed = staged[s0 + i];
        int li = ed.y & 511;
        int pos = atomicAdd(&lcnt[li], 1);
        rec[pos] = ed.x;
    }
}

// ---------- bf16 MFMA GEMM: Cq[n,COLS](bf16) = dscale[r] * (X[n,128] @ W[128,COLS]) ----------
template <int COLS, bool XF32>
__global__ __launch_bounds__(256) void gemm_mfma(const void* __restrict__ Xv,
                                                 const float* __restrict__ W,
                                                 uint* __restrict__ Cq,
                                                 const float* __restrict__ dscale,
                                                 int n) {
    __shared__ ushort sX[64 * 128];
    __shared__ ushort sWT[COLS * 128];
    int t = threadIdx.x;
    int rbase = blockIdx.x * 64;

    if (XF32) {
        const float* X = (const float*)Xv;
#pragma unroll
        for (int i = 0; i < 8; i++) {
            int f = t + 256 * i;
            int r = f >> 5;
            int c4 = f & 31;
            float4 v = make_float4(0.f, 0.f, 0.f, 0.f);
            int gr = rbase + r;
            if (gr < n) v = *(const float4*)(X + (size_t)gr * 128 + c4 * 4);
            uint lo = pack_bf16(v.x, v.y);
            uint hi = pack_bf16(v.z, v.w);
            int chunk = c4 >> 1;
            int sub = (c4 & 1) * 4;
            int off = r * 128 + (((chunk ^ (r & 15)) << 3) + sub);
            *(uint2*)&sX[off] = make_uint2(lo, hi);
        }
    } else {
        const ushort* X = (const ushort*)Xv;
#pragma unroll
        for (int i = 0; i < 4; i++) {
            int f = t + 256 * i;
            int r = f >> 4;
            int chunk = f & 15;
            uint4 v = make_uint4(0, 0, 0, 0);
            int gr = rbase + r;
            if (gr < n) v = *(const uint4*)(X + (size_t)gr * 128 + chunk * 8);
            int off = r * 128 + ((chunk ^ (r & 15)) << 3);
            *(uint4*)&sX[off] = v;
        }
    }
    {
        constexpr int UNITS = 64 * (COLS / 4);
        constexpr int PER_T = UNITS / 256;
#pragma unroll
        for (int i = 0; i < PER_T; i++) {
            int u = t + 256 * i;
            int kp = u / (COLS / 4);
            int n4 = u % (COLS / 4);
            int k = kp * 2;
            float4 w0 = *(const float4*)(W + (size_t)k * COLS + n4 * 4);
            float4 w1 = *(const float4*)(W + (size_t)(k + 1) * COLS + n4 * 4);
            int chunk = k >> 3;
            int sub = k & 7;
            const float* a0 = (const float*)&w0;
            const float* a1 = (const float*)&w1;
#pragma unroll
            for (int j = 0; j < 4; j++) {
                int nn = n4 * 4 + j;
                uint pk = pack_bf16(a0[j], a1[j]);
                int off = nn * 128 + (((chunk ^ (nn & 15)) << 3) + sub);
                *(uint*)&sWT[off] = pk;
            }
        }
    }
    __syncthreads();

    int lane = t & 63;
    int wave = t >> 6;
    int m = lane & 15;
    int q = lane >> 4;
    int r0 = wave * 16;

    floatx4 acc[COLS / 16];
#pragma unroll
    for (int c = 0; c < COLS / 16; c++) acc[c] = (floatx4){0.f, 0.f, 0.f, 0.f};

#pragma unroll
    for (int ks = 0; ks < 4; ks++) {
        int rr = r0 + m;
        int ca = (ks * 4 + q) ^ (rr & 15);
        short8 afrag = *(const short8*)&sX[rr * 128 + (ca << 3)];
#pragma unroll
        for (int c = 0; c < COLS / 16; c++) {
            int nn = c * 16 + m;
            int cb = (ks * 4 + q) ^ (nn & 15);
            short8 bfrag = *(const short8*)&sWT[nn * 128 + (cb << 3)];
            acc[c] = __builtin_amdgcn_mfma_f32_16x16x32_bf16(bfrag, afrag, acc[c], 0, 0, 0);
        }
    }

    int gr = rbase + r0 + m;
    if (gr < n) {
        float sc = dscale[gr];
#pragma unroll
        for (int c = 0; c < COLS / 16; c++) {
            uint2 pk;
            pk.x = pack_bf16(acc[c][0] * sc, acc[c][1] * sc);
            pk.y = pack_bf16(acc[c][2] * sc, acc[c][3] * sc);
            *(uint2*)&Cq[(size_t)gr * (COLS / 2) + c * 8 + q * 2] = pk;
        }
    }
}

// ---------- FUSED: aggregate layer-1 (D=128) + GEMM2 (128->64) ----------
// 256 threads = 16 quarter-waves = 16 nodes/block. hq rows pre-scaled by
// dinv[src]; inner loop is pure gather+add, unrolled 16 edges in flight.
// g tile -> LDS bf16 (swizzled), 4 waves compute h2 = g @ W2 (1x4 tiles)
// and store bf16 pre-scaled by dinv[row].
__global__ __launch_bounds__(256, 5) void agg128_mm64(
    const uint* __restrict__ hq, const int* __restrict__ rec,
    const int4* __restrict__ meta, const float* __restrict__ dinv,
    const float* __restrict__ bias, const float* __restrict__ W2,
    uint* __restrict__ h2q, int n) {
    __shared__ ushort sWT[64 * 128];   // 16 KB
    __shared__ ushort sg[16 * 128];    // 4 KB
    int t = threadIdx.x;

    // stage W2^T (f32 -> bf16, XOR swizzle) — same pattern as gemm_mfma<64>
#pragma unroll
    for (int i = 0; i < 4; i++) {
        int u = t + 256 * i;          // 0..1023 = (kp, n4)
        int kp = u >> 4;
        int n4 = u & 15;
        int k = kp * 2;
        float4 w0 = *(const float4*)(W2 + (size_t)k * 64 + n4 * 4);
        float4 w1 = *(const float4*)(W2 + (size_t)(k + 1) * 64 + n4 * 4);
        int chunk = k >> 3;
        int sub = k & 7;
        const float* a0f = (const float*)&w0;
        const float* a1f = (const float*)&w1;
#pragma unroll
        for (int j = 0; j < 4; j++) {
            int nn = n4 * 4 + j;
            uint pk = pack_bf16(a0f[j], a1f[j]);
            *(uint*)&sWT[nn * 128 + (((chunk ^ (nn & 15)) << 3) + sub)] = pk;
        }
    }

    int qw = t >> 4;                  // 0..15 local node
    int fl = t & 15;                  // uint4 lane: features 8*fl .. 8*fl+7
    int nb0 = blockIdx.x * 16;
    int w = nb0 + qw;
    bool valid = w < n;
    int wsafe = valid ? w : 0;
    const uint4* h4 = (const uint4*)hq;   // row = 16 uint4

    int4 mt = meta[wsafe];
    int j0 = mt.x;
    int deg = valid ? mt.y : 0;
    float di = __int_as_float(mt.z);

    // self term (pre-scaled row, weight 1)
    uint4 qs = h4[(size_t)wsafe * 16 + fl];
    float a0 = bf16_lo(qs.x), a1 = bf16_hi(qs.x);
    float a2 = bf16_lo(qs.y), a3 = bf16_hi(qs.y);
    float a4 = bf16_lo(qs.z), a5 = bf16_hi(qs.z);
    float a6 = bf16_lo(qs.w), a7 = bf16_hi(qs.w);
    if (!valid) { a0 = a1 = a2 = a3 = a4 = a5 = a6 = a7 = 0.f; }

    const int* rp = rec + j0;
    int tt = 0;
    // 16 edges in flight (latency hiding: ~320KB/CU outstanding at 20 waves)
    for (; tt + 16 <= deg; tt += 16) {
        int s[16]; uint4 q[16];
#pragma unroll
        for (int u = 0; u < 16; u++) s[u] = rp[tt + u];
#pragma unroll
        for (int u = 0; u < 16; u++) q[u] = h4[(size_t)s[u] * 16 + fl];
#pragma unroll
        for (int u = 0; u < 16; u++) {
            a0 += bf16_lo(q[u].x); a1 += bf16_hi(q[u].x);
            a2 += bf16_lo(q[u].y); a3 += bf16_hi(q[u].y);
            a4 += bf16_lo(q[u].z); a5 += bf16_hi(q[u].z);
            a6 += bf16_lo(q[u].w); a7 += bf16_hi(q[u].w);
        }
    }
    for (; tt + 8 <= deg; tt += 8) {
        int s[8]; uint4 q[8];
#pragma unroll
        for (int u = 0; u < 8; u++) s[u] = rp[tt + u];
#pragma unroll
        for (int u = 0; u < 8; u++) q[u] = h4[(size_t)s[u] * 16 + fl];
#pragma unroll
        for (int u = 0; u < 8; u++) {
            a0 += bf16_lo(q[u].x); a1 += bf16_hi(q[u].x);
            a2 += bf16_lo(q[u].y); a3 += bf16_hi(q[u].y);
            a4 += bf16_lo(q[u].z); a5 += bf16_hi(q[u].z);
            a6 += bf16_lo(q[u].w); a7 += bf16_hi(q[u].w);
        }
    }
    for (; tt + 2 <= deg; tt += 2) {
        int s0i = rp[tt], s1i = rp[tt + 1];
        uint4 q0 = h4[(size_t)s0i * 16 + fl];
        uint4 q1 = h4[(size_t)s1i * 16 + fl];
        a0 += bf16_lo(q0.x) + bf16_lo(q1.x);
        a1 += bf16_hi(q0.x) + bf16_hi(q1.x);
        a2 += bf16_lo(q0.y) + bf16_lo(q1.y);
        a3 += bf16_hi(q0.y) + bf16_hi(q1.y);
        a4 += bf16_lo(q0.z) + bf16_lo(q1.z);
        a5 += bf16_hi(q0.z) + bf16_hi(q1.z);
        a6 += bf16_lo(q0.w) + bf16_lo(q1.w);
        a7 += bf16_hi(q0.w) + bf16_hi(q1.w);
    }
    if (tt < deg) {
        int s = rp[tt];
        uint4 q0 = h4[(size_t)s * 16 + fl];
        a0 += bf16_lo(q0.x); a1 += bf16_hi(q0.x);
        a2 += bf16_lo(q0.y); a3 += bf16_hi(q0.y);
        a4 += bf16_lo(q0.z); a5 += bf16_hi(q0.z);
        a6 += bf16_lo(q0.w); a7 += bf16_hi(q0.w);
    }

    // g = relu(di*acc + b1) -> bf16 -> LDS (same swizzle as gemm_mfma staging)
    float4 bb0 = *(const float4*)&bias[8 * fl];
    float4 bb1 = *(const float4*)&bias[8 * fl + 4];
    uint4 pkv;
    pkv.x = pack_bf16(fmaxf(di * a0 + bb0.x, 0.f), fmaxf(di * a1 + bb0.y, 0.f));
    pkv.y = pack_bf16(fmaxf(di * a2 + bb0.z, 0.f), fmaxf(di * a3 + bb0.w, 0.f));
    pkv.z = pack_bf16(fmaxf(di * a4 + bb1.x, 0.f), fmaxf(di * a5 + bb1.y, 0.f));
    pkv.w = pack_bf16(fmaxf(di * a6 + bb1.z, 0.f), fmaxf(di * a7 + bb1.w, 0.f));
    *(uint4*)&sg[qw * 128 + ((fl ^ qw) << 3)] = pkv;
    __syncthreads();

    // h2 = g @ W2 : 16 rows x 64 cols, 4 waves = 4 col tiles
    int wave = t >> 6;
    int lane = t & 63;
    int m = lane & 15;
    int qq = lane >> 4;
    int ct = wave;                    // col tile 0..3
    floatx4 acc = (floatx4){0.f, 0.f, 0.f, 0.f};
#pragma unroll
    for (int ks = 0; ks < 4; ks++) {
        int ca = (ks * 4 + qq) ^ m;
        short8 afrag = *(const short8*)&sg[m * 128 + (ca << 3)];
        int nn = ct * 16 + m;
        int cb = (ks * 4 + qq) ^ (nn & 15);
        short8 bfrag = *(const short8*)&sWT[nn * 128 + (cb << 3)];
        acc = __builtin_amdgcn_mfma_f32_16x16x32_bf16(bfrag, afrag, acc, 0, 0, 0);
    }
    int gr = nb0 + m;
    if (gr < n) {
        float sc = dinv[gr];          // pre-scale h2 rows for layer-2 gather
        uint2 pk;
        pk.x = pack_bf16(acc[0] * sc, acc[1] * sc);
        pk.y = pack_bf16(acc[2] * sc, acc[3] * sc);
        *(uint2*)&h2q[(size_t)gr * 32 + ct * 8 + qq * 2] = pk;
    }
}

// ---------- pull aggregation, D=64 (pre-scaled bf16 in, f32 out) ----------
// eighth-wave: 8 lanes x uint4 = 128B row; 16 edges in flight per lane.
__global__ __launch_bounds__(256, 5) void aggregate64q(
    const uint* __restrict__ hq, const int* __restrict__ rec,
    const int4* __restrict__ meta, const float* __restrict__ bias,
    float* __restrict__ out, int n) {
    int gt = blockIdx.x * 256 + threadIdx.x;
    int w = gt >> 3;
    if (w >= n) return;
    int fl = gt & 7;                  // features 8*fl .. 8*fl+7

    int4 mt = meta[w];
    int j0 = mt.x;
    int deg = mt.y;
    float di = __int_as_float(mt.z);
    const uint4* h4 = (const uint4*)hq;   // row = 8 uint4

    uint4 qs = h4[(size_t)w * 8 + fl];
    float a0 = bf16_lo(qs.x), a1 = bf16_hi(qs.x);
    float a2 = bf16_lo(qs.y), a3 = bf16_hi(qs.y);
    float a4 = bf16_lo(qs.z), a5 = bf16_hi(qs.z);
    float a6 = bf16_lo(qs.w), a7 = bf16_hi(qs.w);

    const int* rp = rec + j0;
    int tt = 0;
    for (; tt + 16 <= deg; tt += 16) {
        int s[16]; uint4 q[16];
#pragma unroll
        for (int u = 0; u < 16; u++) s[u] = rp[tt + u];
#pragma unroll
        for (int u = 0; u < 16; u++) q[u] = h4[(size_t)s[u] * 8 + fl];
#pragma unroll
        for (int u = 0; u < 16; u++) {
            a0 += bf16_lo(q[u].x); a1 += bf16_hi(q[u].x);
            a2 += bf16_lo(q[u].y); a3 += bf16_hi(q[u].y);
            a4 += bf16_lo(q[u].z); a5 += bf16_hi(q[u].z);
            a6 += bf16_lo(q[u].w); a7 += bf16_hi(q[u].w);
        }
    }
    for (; tt + 8 <= deg; tt += 8) {
        int s[8]; uint4 q[8];
#pragma unroll
        for (int u = 0; u < 8; u++) s[u] = rp[tt + u];
#pragma unroll
        for (int u = 0; u < 8; u++) q[u] = h4[(size_t)s[u] * 8 + fl];
#pragma unroll
        for (int u = 0; u < 8; u++) {
            a0 += bf16_lo(q[u].x); a1 += bf16_hi(q[u].x);
            a2 += bf16_lo(q[u].y); a3 += bf16_hi(q[u].y);
            a4 += bf16_lo(q[u].z); a5 += bf16_hi(q[u].z);
            a6 += bf16_lo(q[u].w); a7 += bf16_hi(q[u].w);
        }
    }
    for (; tt + 2 <= deg; tt += 2) {
        int s0i = rp[tt], s1i = rp[tt + 1];
        uint4 q0 = h4[(size_t)s0i * 8 + fl];
        uint4 q1 = h4[(size_t)s1i * 8 + fl];
        a0 += bf16_lo(q0.x) + bf16_lo(q1.x);
        a1 += bf16_hi(q0.x) + bf16_hi(q1.x);
        a2 += bf16_lo(q0.y) + bf16_lo(q1.y);
        a3 += bf16_hi(q0.y) + bf16_hi(q1.y);
        a4 += bf16_lo(q0.z) + bf16_lo(q1.z);
        a5 += bf16_hi(q0.z) + bf16_hi(q1.z);
        a6 += bf16_lo(q0.w) + bf16_lo(q1.w);
        a7 += bf16_hi(q0.w) + bf16_hi(q1.w);
    }
    if (tt < deg) {
        int s = rp[tt];
        uint4 q0 = h4[(size_t)s * 8 + fl];
        a0 += bf16_lo(q0.x); a1 += bf16_hi(q0.x);
        a2 += bf16_lo(q0.y); a3 += bf16_hi(q0.y);
        a4 += bf16_lo(q0.z); a5 += bf16_hi(q0.z);
        a6 += bf16_lo(q0.w); a7 += bf16_hi(q0.w);
    }

    float4 bb0 = *(const float4*)&bias[8 * fl];
    float4 bb1 = *(const float4*)&bias[8 * fl + 4];
    float4 o0, o1;
    o0.x = di * a0 + bb0.x; o0.y = di * a1 + bb0.y;
    o0.z = di * a2 + bb0.z; o0.w = di * a3 + bb0.w;
    o1.x = di * a4 + bb1.x; o1.y = di * a5 + bb1.y;
    o1.z = di * a6 + bb1.z; o1.w = di * a7 + bb1.w;
    *(float4*)&out[(size_t)w * 64 + 8 * fl] = o0;
    *(float4*)&out[(size_t)w * 64 + 8 * fl + 4] = o1;
}

extern "C" void kernel_launch(void* const* d_in, const int* in_sizes, int n_in,
                              void* d_out, int out_size, void* d_ws, size_t ws_size,
                              hipStream_t stream) {
    const float* x = (const float*)d_in[0];
    const int* edge = (const int*)d_in[1];
    const float* W1 = (const float*)d_in[2];
    const float* b1 = (const float*)d_in[3];
    const float* W2 = (const float*)d_in[4];
    const float* b2 = (const float*)d_in[5];

    const int N = in_sizes[0] / 128;
    const int E = in_sizes[1] / 2;
    const int* src = edge;
    const int* dst = edge + E;
    const int NB = (N + (1 << BSH) - 1) >> BSH;   // coarse buckets (<= 256)

    // workspace carve-up (all chunks 16B-aligned for these sizes)
    char* p = (char*)d_ws;
    int* bcnt = (int*)p;      p += NBMAX * 4;
    int* bstart = (int*)p;    p += NBMAX * 4;
    int* bcursor = (int*)p;   p += NBMAX * 4;
    float* dinv = (float*)p;  p += (size_t)N * 4;
    int4* meta = (int4*)p;    p += (size_t)N * 16;      // (start, deg, dinv, dinv^2)
    int* rec = (int*)p;       p += (size_t)E * 4;       // src per edge (CSR by dst)
    int2* staged = (int2*)p;  p += (size_t)E * 8;       // (src,dst) bucket-grouped
    uint* hq = (uint*)p;      p += (size_t)N * 64 * 4;  // dinv[r]*(x@W1), bf16 pairs
    uint* h2q = (uint*)p;     p += (size_t)N * 32 * 4;  // dinv[r]*h2, bf16 (64 feats)

    float* out = (float*)d_out;
    const int eblocks = (E + 2047) / 2048;

    // CSR build (two-level bucketed, zero per-node global atomics)
    (void)hipMemsetAsync(bcnt, 0, NBMAX * 4, stream);
    bucket_hist_kernel<<<eblocks, 256, 0, stream>>>(dst, bcnt, E, NB);
    bucket_scan<<<1, NBMAX, 0, stream>>>(bcnt, bstart, bcursor, NB);
    partition_kernel<<<eblocks, 256, 0, stream>>>(src, dst, bcursor, staged, E, NB);
    fine_csr_kernel<<<NB, 256, 0, stream>>>(staged, bstart, bcnt, meta, dinv, rec, N);

    const int gblocks = (N + 63) / 64;

    // layer 1 GEMM: hq = dinv .* (x @ W1) (bf16, pre-scaled rows)
    gemm_mfma<128, true><<<gblocks, 256, 0, stream>>>(x, W1, hq, dinv, N);
    // fused: g = relu(di*(sum of pre-scaled rows) + b1); h2q = dinv .* (g @ W2)
    agg128_mm64<<<(N + 15) / 16, 256, 0, stream>>>(hq, rec, meta, dinv, b1, W2, h2q, N);
    // layer 2 aggregation: out = di*(sum of pre-scaled h2 rows) + b2
    aggregate64q<<<(N * 8 + 255) / 256, 256, 0, stream>>>(h2q, rec, meta, b2, out, N);
}

// Round 3
// 294.272 us; speedup vs baseline: 1.2540x; 1.2540x over previous
//
#include <hip/hip_runtime.h>
#include <hip/hip_bf16.h>

// GCN 2-layer: h = relu(Anorm @ (x@W1) + b1); out = Anorm @ (h@W2) + b2
// R12 changes vs R11:
//  - REVERT agg128_mm64 / aggregate64q to R10 forms (R11's U=16 +
//    launch_bounds(256,5) spilled: +228MB scratch traffic, +53us).
//  - CSR build reworked: BSH 9->8 (256 nodes/bucket, NB=391 blocks ->
//    2x fine_csr parallelism, half the per-block serial depth),
//    staged[] packed to one uint (src<<8 | dst&255) halving its bytes,
//    fine_csr caches the bucket's edges in LDS (fill pass reads LDS,
//    not a second global pass).

#define NTHREADS 256
#define BSH 8                 // bucket = dst >> 8 (256 nodes/bucket)
#define NBMAX 512
#define FC_CAP 8192           // LDS edge cache per bucket (mean 4096, sigma 64)

typedef unsigned int uint;
typedef unsigned short ushort;
typedef __attribute__((ext_vector_type(8))) short short8;
typedef __attribute__((ext_vector_type(4))) float floatx4;

__device__ __forceinline__ uint pack_bf16(float a, float b) {
    __hip_bfloat162 h = __float22bfloat162_rn(make_float2(a, b));
    return *reinterpret_cast<uint*>(&h);
}
__device__ __forceinline__ float bf16_lo(uint q) { return __uint_as_float(q << 16); }
__device__ __forceinline__ float bf16_hi(uint q) { return __uint_as_float(q & 0xffff0000u); }

// ---------- coarse bucket histogram only (no per-node atomics) ----------
__global__ __launch_bounds__(256) void bucket_hist_kernel(
    const int* __restrict__ dst, int* __restrict__ bcnt, int e, int nb) {
    __shared__ int hist[NBMAX];
    int t = threadIdx.x;
    for (int b = t; b < nb; b += 256) hist[b] = 0;
    __syncthreads();
    int e0 = blockIdx.x * 2048;
#pragma unroll
    for (int v = 0; v < 2; v++) {
        int gi = e0 + t * 8 + v * 4;
        if (gi + 3 < e) {
            int4 d4 = *(const int4*)&dst[gi];
            atomicAdd(&hist[d4.x >> BSH], 1);
            atomicAdd(&hist[d4.y >> BSH], 1);
            atomicAdd(&hist[d4.z >> BSH], 1);
            atomicAdd(&hist[d4.w >> BSH], 1);
        } else {
            for (int j = 0; j < 4; j++)
                if (gi + j < e) atomicAdd(&hist[dst[gi + j] >> BSH], 1);
        }
    }
    __syncthreads();
    for (int b = t; b < nb; b += 256) {
        int v = hist[b];
        if (v) atomicAdd(&bcnt[b], v);
    }
}

// ---------- bucket scan (nb <= 512, single block of 512) ----------
__global__ void bucket_scan(const int* __restrict__ bcnt, int* __restrict__ bstart,
                            int* __restrict__ bcursor, int nb) {
    __shared__ int buf[NBMAX];
    int t = threadIdx.x;
    int v = (t < nb) ? bcnt[t] : 0;
    buf[t] = v;
    __syncthreads();
    int x = v;
    for (int off = 1; off < NBMAX; off <<= 1) {
        int y = (t >= off) ? buf[t - off] : 0;
        __syncthreads();
        x += y;
        buf[t] = x;
        __syncthreads();
    }
    if (t < nb) {
        bstart[t] = x - v;
        bcursor[t] = x - v;
    }
}

// ---------- coarse partition: staged[] = packed (src<<8|dloc) by bucket ----------
__global__ __launch_bounds__(256) void partition_kernel(
    const int* __restrict__ src, const int* __restrict__ dst,
    int* __restrict__ bcursor, uint* __restrict__ staged, int e, int nb) {
    __shared__ uint eP[2048];        // packed (src<<8 | dst&255)
    __shared__ ushort eB[2048];      // bucket id (0xFFFF = invalid)
    __shared__ int hist[NBMAX];
    __shared__ int base[NBMAX];
    int t = threadIdx.x;
    int e0 = blockIdx.x * 2048;

    for (int b = t; b < nb; b += 256) hist[b] = 0;
    __syncthreads();
#pragma unroll
    for (int v = 0; v < 2; v++) {
        int li = t * 8 + v * 4;
        int gi = e0 + li;
        int4 s4, d4;
        if (gi + 3 < e) {
            s4 = *(const int4*)&src[gi];
            d4 = *(const int4*)&dst[gi];
        } else {
            const int* sp = &src[gi];
            const int* dp = &dst[gi];
            s4.x = (gi + 0 < e) ? sp[0] : 0;  d4.x = (gi + 0 < e) ? dp[0] : -1;
            s4.y = (gi + 1 < e) ? sp[1] : 0;  d4.y = (gi + 1 < e) ? dp[1] : -1;
            s4.z = (gi + 2 < e) ? sp[2] : 0;  d4.z = (gi + 2 < e) ? dp[2] : -1;
            s4.w = (gi + 3 < e) ? sp[3] : 0;  d4.w = (gi + 3 < e) ? dp[3] : -1;
        }
        uint4 p4;
        p4.x = ((uint)s4.x << 8) | ((uint)d4.x & 255u);
        p4.y = ((uint)s4.y << 8) | ((uint)d4.y & 255u);
        p4.z = ((uint)s4.z << 8) | ((uint)d4.z & 255u);
        p4.w = ((uint)s4.w << 8) | ((uint)d4.w & 255u);
        *(uint4*)&eP[li] = p4;
        eB[li + 0] = (d4.x >= 0) ? (ushort)(d4.x >> BSH) : (ushort)0xFFFF;
        eB[li + 1] = (d4.y >= 0) ? (ushort)(d4.y >> BSH) : (ushort)0xFFFF;
        eB[li + 2] = (d4.z >= 0) ? (ushort)(d4.z >> BSH) : (ushort)0xFFFF;
        eB[li + 3] = (d4.w >= 0) ? (ushort)(d4.w >> BSH) : (ushort)0xFFFF;
        if (d4.x >= 0) atomicAdd(&hist[d4.x >> BSH], 1);
        if (d4.y >= 0) atomicAdd(&hist[d4.y >> BSH], 1);
        if (d4.z >= 0) atomicAdd(&hist[d4.z >> BSH], 1);
        if (d4.w >= 0) atomicAdd(&hist[d4.w >> BSH], 1);
    }
    __syncthreads();
    for (int b = t; b < nb; b += 256) {
        int v = hist[b];
        base[b] = v ? atomicAdd(&bcursor[b], v) : 0;
        hist[b] = 0;   // reset for rank pass
    }
    __syncthreads();
#pragma unroll
    for (int i = 0; i < 8; i++) {
        int li = t + i * 256;
        ushort bb = eB[li];
        if (bb != (ushort)0xFFFF) {
            int r = atomicAdd(&hist[bb], 1);
            staged[base[bb] + r] = eP[li];
        }
    }
}

// ---------- per-bucket fused CSR: count+scan -> meta/dinv, LDS-cached fill ----------
__global__ __launch_bounds__(256) void fine_csr_kernel(
    const uint* __restrict__ staged, const int* __restrict__ bstart,
    const int* __restrict__ bcnt, int4* __restrict__ meta,
    float* __restrict__ dinv, int* __restrict__ rec, int n) {
    __shared__ uint eL[FC_CAP];      // 32 KB edge cache
    __shared__ int lcnt[256];
    __shared__ int tsum[256];
    int b = blockIdx.x;
    int t = threadIdx.x;
    lcnt[t] = 0;
    __syncthreads();
    int s0 = bstart[b];
    int m = bcnt[b];
    for (int i = t; i < m; i += 256) {
        uint pk = staged[s0 + i];
        if (i < FC_CAP) eL[i] = pk;
        atomicAdd(&lcnt[pk & 255u], 1);
    }
    __syncthreads();
    int v = lcnt[t];
    tsum[t] = v;
    __syncthreads();
    int x = v;
    for (int off = 1; off < 256; off <<= 1) {
        int y = (t >= off) ? tsum[t - off] : 0;
        __syncthreads();
        x += y;
        tsum[t] = x;
        __syncthreads();
    }
    int excl = x - v;
    int node = (b << BSH) + t;
    if (node < n) {
        float di = rsqrtf((float)v + 1.0f);
        dinv[node] = di;
        meta[node] = make_int4(s0 + excl, v, __float_as_int(di), __float_as_int(di * di));
    }
    lcnt[t] = s0 + excl;             // repurpose as absolute cursor
    __syncthreads();
    // fill: rec[pos] = src (edges come from LDS cache)
    for (int i = t; i < m; i += 256) {
        uint pk = (i < FC_CAP) ? eL[i] : staged[s0 + i];
        int pos = atomicAdd(&lcnt[pk & 255u], 1);
        rec[pos] = (int)(pk >> 8);
    }
}

// ---------- bf16 MFMA GEMM: Cq[n,COLS](bf16) = dscale[r] * (X[n,128] @ W[128,COLS]) ----------
template <int COLS, bool XF32>
__global__ __launch_bounds__(256) void gemm_mfma(const void* __restrict__ Xv,
                                                 const float* __restrict__ W,
                                                 uint* __restrict__ Cq,
                                                 const float* __restrict__ dscale,
                                                 int n) {
    __shared__ ushort sX[64 * 128];
    __shared__ ushort sWT[COLS * 128];
    int t = threadIdx.x;
    int rbase = blockIdx.x * 64;

    if (XF32) {
        const float* X = (const float*)Xv;
#pragma unroll
        for (int i = 0; i < 8; i++) {
            int f = t + 256 * i;
            int r = f >> 5;
            int c4 = f & 31;
            float4 v = make_float4(0.f, 0.f, 0.f, 0.f);
            int gr = rbase + r;
            if (gr < n) v = *(const float4*)(X + (size_t)gr * 128 + c4 * 4);
            uint lo = pack_bf16(v.x, v.y);
            uint hi = pack_bf16(v.z, v.w);
            int chunk = c4 >> 1;
            int sub = (c4 & 1) * 4;
            int off = r * 128 + (((chunk ^ (r & 15)) << 3) + sub);
            *(uint2*)&sX[off] = make_uint2(lo, hi);
        }
    } else {
        const ushort* X = (const ushort*)Xv;
#pragma unroll
        for (int i = 0; i < 4; i++) {
            int f = t + 256 * i;
            int r = f >> 4;
            int chunk = f & 15;
            uint4 v = make_uint4(0, 0, 0, 0);
            int gr = rbase + r;
            if (gr < n) v = *(const uint4*)(X + (size_t)gr * 128 + chunk * 8);
            int off = r * 128 + ((chunk ^ (r & 15)) << 3);
            *(uint4*)&sX[off] = v;
        }
    }
    {
        constexpr int UNITS = 64 * (COLS / 4);
        constexpr int PER_T = UNITS / 256;
#pragma unroll
        for (int i = 0; i < PER_T; i++) {
            int u = t + 256 * i;
            int kp = u / (COLS / 4);
            int n4 = u % (COLS / 4);
            int k = kp * 2;
            float4 w0 = *(const float4*)(W + (size_t)k * COLS + n4 * 4);
            float4 w1 = *(const float4*)(W + (size_t)(k + 1) * COLS + n4 * 4);
            int chunk = k >> 3;
            int sub = k & 7;
            const float* a0 = (const float*)&w0;
            const float* a1 = (const float*)&w1;
#pragma unroll
            for (int j = 0; j < 4; j++) {
                int nn = n4 * 4 + j;
                uint pk = pack_bf16(a0[j], a1[j]);
                int off = nn * 128 + (((chunk ^ (nn & 15)) << 3) + sub);
                *(uint*)&sWT[off] = pk;
            }
        }
    }
    __syncthreads();

    int lane = t & 63;
    int wave = t >> 6;
    int m = lane & 15;
    int q = lane >> 4;
    int r0 = wave * 16;

    floatx4 acc[COLS / 16];
#pragma unroll
    for (int c = 0; c < COLS / 16; c++) acc[c] = (floatx4){0.f, 0.f, 0.f, 0.f};

#pragma unroll
    for (int ks = 0; ks < 4; ks++) {
        int rr = r0 + m;
        int ca = (ks * 4 + q) ^ (rr & 15);
        short8 afrag = *(const short8*)&sX[rr * 128 + (ca << 3)];
#pragma unroll
        for (int c = 0; c < COLS / 16; c++) {
            int nn = c * 16 + m;
            int cb = (ks * 4 + q) ^ (nn & 15);
            short8 bfrag = *(const short8*)&sWT[nn * 128 + (cb << 3)];
            acc[c] = __builtin_amdgcn_mfma_f32_16x16x32_bf16(bfrag, afrag, acc[c], 0, 0, 0);
        }
    }

    int gr = rbase + r0 + m;
    if (gr < n) {
        float sc = dscale[gr];
#pragma unroll
        for (int c = 0; c < COLS / 16; c++) {
            uint2 pk;
            pk.x = pack_bf16(acc[c][0] * sc, acc[c][1] * sc);
            pk.y = pack_bf16(acc[c][2] * sc, acc[c][3] * sc);
            *(uint2*)&Cq[(size_t)gr * (COLS / 2) + c * 8 + q * 2] = pk;
        }
    }
}

// ---------- FUSED: aggregate layer-1 (D=128) + GEMM2 (128->64) ----------
// 512 threads = 32 quarter-waves = 32 nodes/block (R10 form, proven).
__global__ __launch_bounds__(512) void agg128_mm64(
    const uint* __restrict__ hq, const int* __restrict__ rec,
    const int4* __restrict__ meta, const float* __restrict__ dinv,
    const float* __restrict__ bias, const float* __restrict__ W2,
    uint* __restrict__ h2q, int n) {
    __shared__ ushort sWT[64 * 128];   // 16 KB
    __shared__ ushort sg[32 * 128];    // 8 KB
    int t = threadIdx.x;

    // stage W2^T (f32 -> bf16, XOR swizzle) — same pattern as gemm_mfma<64>
#pragma unroll
    for (int i = 0; i < 2; i++) {
        int u = t + 512 * i;          // 0..1023 = (kp, n4)
        int kp = u >> 4;
        int n4 = u & 15;
        int k = kp * 2;
        float4 w0 = *(const float4*)(W2 + (size_t)k * 64 + n4 * 4);
        float4 w1 = *(const float4*)(W2 + (size_t)(k + 1) * 64 + n4 * 4);
        int chunk = k >> 3;
        int sub = k & 7;
        const float* a0f = (const float*)&w0;
        const float* a1f = (const float*)&w1;
#pragma unroll
        for (int j = 0; j < 4; j++) {
            int nn = n4 * 4 + j;
            uint pk = pack_bf16(a0f[j], a1f[j]);
            *(uint*)&sWT[nn * 128 + (((chunk ^ (nn & 15)) << 3) + sub)] = pk;
        }
    }

    int qw = t >> 4;                  // 0..31 local node
    int fl = t & 15;                  // uint4 lane: features 8*fl .. 8*fl+7
    int nb0 = blockIdx.x * 32;
    int w = nb0 + qw;
    bool valid = w < n;
    int wsafe = valid ? w : 0;
    const uint4* h4 = (const uint4*)hq;   // row = 16 uint4

    int4 mt = meta[wsafe];
    int j0 = mt.x;
    int deg = valid ? mt.y : 0;
    float di = __int_as_float(mt.z);

    // self term (pre-scaled row, weight 1)
    uint4 qs = h4[(size_t)wsafe * 16 + fl];
    float a0 = bf16_lo(qs.x), a1 = bf16_hi(qs.x);
    float a2 = bf16_lo(qs.y), a3 = bf16_hi(qs.y);
    float a4 = bf16_lo(qs.z), a5 = bf16_hi(qs.z);
    float a6 = bf16_lo(qs.w), a7 = bf16_hi(qs.w);
    if (!valid) { a0 = a1 = a2 = a3 = a4 = a5 = a6 = a7 = 0.f; }

    const int* rp = rec + j0;
    int tt = 0;
    for (; tt + 8 <= deg; tt += 8) {
        int s[8]; uint4 q[8];
#pragma unroll
        for (int u = 0; u < 8; u++) s[u] = rp[tt + u];
#pragma unroll
        for (int u = 0; u < 8; u++) q[u] = h4[(size_t)s[u] * 16 + fl];
#pragma unroll
        for (int u = 0; u < 8; u++) {
            a0 += bf16_lo(q[u].x); a1 += bf16_hi(q[u].x);
            a2 += bf16_lo(q[u].y); a3 += bf16_hi(q[u].y);
            a4 += bf16_lo(q[u].z); a5 += bf16_hi(q[u].z);
            a6 += bf16_lo(q[u].w); a7 += bf16_hi(q[u].w);
        }
    }
    for (; tt + 2 <= deg; tt += 2) {
        int s0i = rp[tt], s1i = rp[tt + 1];
        uint4 q0 = h4[(size_t)s0i * 16 + fl];
        uint4 q1 = h4[(size_t)s1i * 16 + fl];
        a0 += bf16_lo(q0.x) + bf16_lo(q1.x);
        a1 += bf16_hi(q0.x) + bf16_hi(q1.x);
        a2 += bf16_lo(q0.y) + bf16_lo(q1.y);
        a3 += bf16_hi(q0.y) + bf16_hi(q1.y);
        a4 += bf16_lo(q0.z) + bf16_lo(q1.z);
        a5 += bf16_hi(q0.z) + bf16_hi(q1.z);
        a6 += bf16_lo(q0.w) + bf16_lo(q1.w);
        a7 += bf16_hi(q0.w) + bf16_hi(q1.w);
    }
    if (tt < deg) {
        int s = rp[tt];
        uint4 q0 = h4[(size_t)s * 16 + fl];
        a0 += bf16_lo(q0.x); a1 += bf16_hi(q0.x);
        a2 += bf16_lo(q0.y); a3 += bf16_hi(q0.y);
        a4 += bf16_lo(q0.z); a5 += bf16_hi(q0.z);
        a6 += bf16_lo(q0.w); a7 += bf16_hi(q0.w);
    }

    // g = relu(di*acc + b1) -> bf16 -> LDS (same swizzle as gemm_mfma staging)
    float4 bb0 = *(const float4*)&bias[8 * fl];
    float4 bb1 = *(const float4*)&bias[8 * fl + 4];
    uint4 pkv;
    pkv.x = pack_bf16(fmaxf(di * a0 + bb0.x, 0.f), fmaxf(di * a1 + bb0.y, 0.f));
    pkv.y = pack_bf16(fmaxf(di * a2 + bb0.z, 0.f), fmaxf(di * a3 + bb0.w, 0.f));
    pkv.z = pack_bf16(fmaxf(di * a4 + bb1.x, 0.f), fmaxf(di * a5 + bb1.y, 0.f));
    pkv.w = pack_bf16(fmaxf(di * a6 + bb1.z, 0.f), fmaxf(di * a7 + bb1.w, 0.f));
    *(uint4*)&sg[qw * 128 + ((fl ^ (qw & 15)) << 3)] = pkv;
    __syncthreads();

    // h2 = g @ W2 : 32 rows x 64 cols, 8 waves = 2 row-tiles x 4 col-tiles
    int wave = t >> 6;
    int lane = t & 63;
    int m = lane & 15;
    int qq = lane >> 4;
    int rt = wave >> 2;               // row tile 0..1
    int ct = wave & 3;                // col tile 0..3
    floatx4 acc = (floatx4){0.f, 0.f, 0.f, 0.f};
#pragma unroll
    for (int ks = 0; ks < 4; ks++) {
        int rr = rt * 16 + m;
        int ca = (ks * 4 + qq) ^ (rr & 15);
        short8 afrag = *(const short8*)&sg[rr * 128 + (ca << 3)];
        int nn = ct * 16 + m;
        int cb = (ks * 4 + qq) ^ (nn & 15);
        short8 bfrag = *(const short8*)&sWT[nn * 128 + (cb << 3)];
        acc = __builtin_amdgcn_mfma_f32_16x16x32_bf16(bfrag, afrag, acc, 0, 0, 0);
    }
    int gr = nb0 + rt * 16 + m;
    if (gr < n) {
        float sc = dinv[gr];          // pre-scale h2 rows for layer-2 gather
        uint2 pk;
        pk.x = pack_bf16(acc[0] * sc, acc[1] * sc);
        pk.y = pack_bf16(acc[2] * sc, acc[3] * sc);
        *(uint2*)&h2q[(size_t)gr * 32 + ct * 8 + qq * 2] = pk;
    }
}

// ---------- pull aggregation, D=64 (pre-scaled bf16 in, f32 out) ----------
// eighth-wave: 8 lanes x uint4 = 128B row (R10 form, proven).
__global__ __launch_bounds__(256) void aggregate64q(
    const uint* __restrict__ hq, const int* __restrict__ rec,
    const int4* __restrict__ meta, const float* __restrict__ bias,
    float* __restrict__ out, int n) {
    int gt = blockIdx.x * 256 + threadIdx.x;
    int w = gt >> 3;
    if (w >= n) return;
    int fl = gt & 7;                  // features 8*fl .. 8*fl+7

    int4 mt = meta[w];
    int j0 = mt.x;
    int deg = mt.y;
    float di = __int_as_float(mt.z);
    const uint4* h4 = (const uint4*)hq;   // row = 8 uint4

    uint4 qs = h4[(size_t)w * 8 + fl];
    float a0 = bf16_lo(qs.x), a1 = bf16_hi(qs.x);
    float a2 = bf16_lo(qs.y), a3 = bf16_hi(qs.y);
    float a4 = bf16_lo(qs.z), a5 = bf16_hi(qs.z);
    float a6 = bf16_lo(qs.w), a7 = bf16_hi(qs.w);

    const int* rp = rec + j0;
    int tt = 0;
    for (; tt + 8 <= deg; tt += 8) {
        int s[8]; uint4 q[8];
#pragma unroll
        for (int u = 0; u < 8; u++) s[u] = rp[tt + u];
#pragma unroll
        for (int u = 0; u < 8; u++) q[u] = h4[(size_t)s[u] * 8 + fl];
#pragma unroll
        for (int u = 0; u < 8; u++) {
            a0 += bf16_lo(q[u].x); a1 += bf16_hi(q[u].x);
            a2 += bf16_lo(q[u].y); a3 += bf16_hi(q[u].y);
            a4 += bf16_lo(q[u].z); a5 += bf16_hi(q[u].z);
            a6 += bf16_lo(q[u].w); a7 += bf16_hi(q[u].w);
        }
    }
    for (; tt + 2 <= deg; tt += 2) {
        int s0i = rp[tt], s1i = rp[tt + 1];
        uint4 q0 = h4[(size_t)s0i * 8 + fl];
        uint4 q1 = h4[(size_t)s1i * 8 + fl];
        a0 += bf16_lo(q0.x) + bf16_lo(q1.x);
        a1 += bf16_hi(q0.x) + bf16_hi(q1.x);
        a2 += bf16_lo(q0.y) + bf16_lo(q1.y);
        a3 += bf16_hi(q0.y) + bf16_hi(q1.y);
        a4 += bf16_lo(q0.z) + bf16_lo(q1.z);
        a5 += bf16_hi(q0.z) + bf16_hi(q1.z);
        a6 += bf16_lo(q0.w) + bf16_lo(q1.w);
        a7 += bf16_hi(q0.w) + bf16_hi(q1.w);
    }
    if (tt < deg) {
        int s = rp[tt];
        uint4 q0 = h4[(size_t)s * 8 + fl];
        a0 += bf16_lo(q0.x); a1 += bf16_hi(q0.x);
        a2 += bf16_lo(q0.y); a3 += bf16_hi(q0.y);
        a4 += bf16_lo(q0.z); a5 += bf16_hi(q0.z);
        a6 += bf16_lo(q0.w); a7 += bf16_hi(q0.w);
    }

    float4 bb0 = *(const float4*)&bias[8 * fl];
    float4 bb1 = *(const float4*)&bias[8 * fl + 4];
    float4 o0, o1;
    o0.x = di * a0 + bb0.x; o0.y = di * a1 + bb0.y;
    o0.z = di * a2 + bb0.z; o0.w = di * a3 + bb0.w;
    o1.x = di * a4 + bb1.x; o1.y = di * a5 + bb1.y;
    o1.z = di * a6 + bb1.z; o1.w = di * a7 + bb1.w;
    *(float4*)&out[(size_t)w * 64 + 8 * fl] = o0;
    *(float4*)&out[(size_t)w * 64 + 8 * fl + 4] = o1;
}

extern "C" void kernel_launch(void* const* d_in, const int* in_sizes, int n_in,
                              void* d_out, int out_size, void* d_ws, size_t ws_size,
                              hipStream_t stream) {
    const float* x = (const float*)d_in[0];
    const int* edge = (const int*)d_in[1];
    const float* W1 = (const float*)d_in[2];
    const float* b1 = (const float*)d_in[3];
    const float* W2 = (const float*)d_in[4];
    const float* b2 = (const float*)d_in[5];

    const int N = in_sizes[0] / 128;
    const int E = in_sizes[1] / 2;
    const int* src = edge;
    const int* dst = edge + E;
    const int NB = (N + (1 << BSH) - 1) >> BSH;   // coarse buckets (<= 512)

    // workspace carve-up (all chunks 16B-aligned for these sizes)
    char* p = (char*)d_ws;
    int* bcnt = (int*)p;      p += NBMAX * 4;
    int* bstart = (int*)p;    p += NBMAX * 4;
    int* bcursor = (int*)p;   p += NBMAX * 4;
    float* dinv = (float*)p;  p += (size_t)N * 4;
    int4* meta = (int4*)p;    p += (size_t)N * 16;      // (start, deg, dinv, dinv^2)
    int* rec = (int*)p;       p += (size_t)E * 4;       // src per edge (CSR by dst)
    uint* staged = (uint*)p;  p += (size_t)E * 4;       // packed (src<<8|dloc)
    uint* hq = (uint*)p;      p += (size_t)N * 64 * 4;  // dinv[r]*(x@W1), bf16 pairs
    uint* h2q = (uint*)p;     p += (size_t)N * 32 * 4;  // dinv[r]*h2, bf16 (64 feats)

    float* out = (float*)d_out;
    const int eblocks = (E + 2047) / 2048;

    // CSR build (two-level bucketed, zero per-node global atomics)
    (void)hipMemsetAsync(bcnt, 0, NBMAX * 4, stream);
    bucket_hist_kernel<<<eblocks, 256, 0, stream>>>(dst, bcnt, E, NB);
    bucket_scan<<<1, NBMAX, 0, stream>>>(bcnt, bstart, bcursor, NB);
    partition_kernel<<<eblocks, 256, 0, stream>>>(src, dst, bcursor, staged, E, NB);
    fine_csr_kernel<<<NB, 256, 0, stream>>>(staged, bstart, bcnt, meta, dinv, rec, N);

    const int gblocks = (N + 63) / 64;

    // layer 1 GEMM: hq = dinv .* (x @ W1) (bf16, pre-scaled rows)
    gemm_mfma<128, true><<<gblocks, 256, 0, stream>>>(x, W1, hq, dinv, N);
    // fused: g = relu(di*(sum of pre-scaled rows) + b1); h2q = dinv .* (g @ W2)
    agg128_mm64<<<(N + 31) / 32, 512, 0, stream>>>(hq, rec, meta, dinv, b1, W2, h2q, N);
    // layer 2 aggregation: out = di*(sum of pre-scaled h2 rows) + b2
    aggregate64q<<<(N * 8 + 255) / 256, 256, 0, stream>>>(h2q, rec, meta, b2, out, N);
}